// Round 13
// baseline (499.983 us; speedup 1.0000x reference)
//
#include <hip/hip_runtime.h>

#define DD 8
#define HH 56
#define WW 56
#define HWW (HH*WW)
#define NTOK (DD*HH*WW)      // 25088
#define BB 4
#define CC 128
#define NH 8
#define HD 16
#define MTOT (BB*NTOK)       // 100352

typedef __attribute__((ext_vector_type(8))) short bf16x8;
typedef __attribute__((ext_vector_type(4))) float f32x4;

__device__ __forceinline__ unsigned short f2bf(float f){
    unsigned int u = __float_as_uint(f);
    u += 0x7FFFu + ((u>>16)&1u);
    return (unsigned short)(u>>16);
}
__device__ __forceinline__ float bf2f(unsigned short s){
    return __uint_as_float(((unsigned int)s)<<16);
}

// ---------- Pre-kernel: weights -> FRAGMENT-ORDERED bf16 hi/lo (unchanged) ----------
__global__ __launch_bounds__(256)
void wsplit_kernel(const float* __restrict__ qw, const float* __restrict__ kvw,
                   const float* __restrict__ pw,
                   unsigned short* __restrict__ wfhi, unsigned short* __restrict__ wflo,
                   unsigned short* __restrict__ pwfhi, unsigned short* __restrict__ pwflo)
{
    int idx = blockIdx.x*256 + threadIdx.x;   // 0..65535
    int e  = idx&7;
    int l  = (idx>>3)&63;
    int ks = (idx>>9)&3;
    int ct = idx>>11;                         // 0..31
    int lr = l&15, lg = l>>4;
    int k  = ks*32 + lg*8 + e;
    if (ct < 24){
        int c = ct*16 + lr;
        float s = (c<CC) ? qw[c*CC+k] : kvw[(c-CC)*CC+k];
        unsigned short h = f2bf(s);
        unsigned short lo = f2bf(s - bf2f(h));
        wfhi[idx]=h; wflo[idx]=lo;
    } else {
        int c = (ct-24)*16 + lr;
        float s = pw[c*CC+k];
        unsigned short h = f2bf(s);
        unsigned short lo = f2bf(s - bf2f(h));
        int o = idx - 49152;
        pwfhi[o]=h; pwflo[o]=lo;
    }
}

// ---------- Kernel A: QKV — LDS-staged A, fragment B, LDS-transpose epilogue ----------
__global__ __launch_bounds__(256,3)
void qkv_kernel(const float* __restrict__ x,
                const float* __restrict__ qb, const float* __restrict__ kvb,
                const unsigned short* __restrict__ wfhi, const unsigned short* __restrict__ wflo,
                const float* __restrict__ temp, const float* __restrict__ qemb,
                float* __restrict__ qbuf, float* __restrict__ kbuf,
                unsigned short* __restrict__ vbuf)
{
    __shared__ float xs[64*132];              // 33.8KB: A-stage (chunk layout) then epilogue (row*132+col)
    const int t  = threadIdx.x;
    const int wv = t>>6;
    const int l  = t&63;
    const int lr = l&15;
    const int lg = l>>4;
    const int m0 = blockIdx.x*64;

    // ---- stage A: coalesced global read, XOR chunk-swizzled LDS write ----
    #pragma unroll
    for (int i=0;i<8;++i){
        int p = i*256 + t;
        int row = p>>5, c = p&31;
        float4 v = *reinterpret_cast<const float4*>(x + (size_t)(m0+row)*CC + c*4);
        int ch = row*32 + (c ^ (row&7));
        *reinterpret_cast<float4*>(xs + ch*4) = v;
    }
    __syncthreads();

    f32x4 acc[4][6];
    #pragma unroll
    for (int j=0;j<6;++j){
        int col = (wv*6+j)*16 + lr;
        float b = (col<CC) ? qb[col] : kvb[col-CC];
        #pragma unroll
        for (int rt=0;rt<4;++rt) acc[rt][j] = (f32x4){b,b,b,b};
    }

    #pragma unroll
    for (int ks=0; ks<4; ++ks){
        bf16x8 ahi[4], alo[4];
        #pragma unroll
        for (int rt=0;rt<4;++rt){
            int row = rt*16 + lr;
            int c0  = ks*8 + lg*2;
            float4 a0 = *reinterpret_cast<const float4*>(xs + (row*32 + ( c0   ^(row&7)))*4);
            float4 a1 = *reinterpret_cast<const float4*>(xs + (row*32 + ((c0+1)^(row&7)))*4);
            float xf[8] = {a0.x,a0.y,a0.z,a0.w, a1.x,a1.y,a1.z,a1.w};
            #pragma unroll
            for (int jj=0;jj<8;++jj){
                unsigned short h = f2bf(xf[jj]);
                unsigned short lo2 = f2bf(xf[jj] - bf2f(h));
                ahi[rt][jj] = (short)h;
                alo[rt][jj] = (short)lo2;
            }
        }
        #pragma unroll
        for (int j=0;j<6;++j){
            const int ct = wv*6+j;
            const size_t off = (size_t)(((ct*4+ks)*64 + l))*8;
            bf16x8 bhi = *reinterpret_cast<const bf16x8*>(wfhi + off);
            bf16x8 blo = *reinterpret_cast<const bf16x8*>(wflo + off);
            #pragma unroll
            for (int rt=0;rt<4;++rt){
                acc[rt][j] = __builtin_amdgcn_mfma_f32_16x16x32_bf16(ahi[rt], bhi, acc[rt][j], 0,0,0);
                acc[rt][j] = __builtin_amdgcn_mfma_f32_16x16x32_bf16(alo[rt], bhi, acc[rt][j], 0,0,0);
                acc[rt][j] = __builtin_amdgcn_mfma_f32_16x16x32_bf16(ahi[rt], blo, acc[rt][j], 0,0,0);
            }
        }
    }

    // seq-scale factors (q only)
    float slog[4][4];
    #pragma unroll
    for (int rt=0;rt<4;++rt){
        #pragma unroll
        for (int r=0;r<4;++r){
            int row = m0 + rt*16 + lg*4 + r;
            int n = row % NTOK;
            int z = n / HWW; int rem = n - z*HWW;
            int y = rem / WW; int xx = rem - y*WW;
            const float L2c = 0.69314718f, L3c = 1.09861229f;
            slog[rt][r] = ((z==0||z==DD-1)?L2c:L3c) + ((y==0||y==HH-1)?L2c:L3c) + ((xx==0||xx==WW-1)?L2c:L3c);
        }
    }

    __syncthreads();   // A-tile reads done; xs reused for epilogue staging

    // ---- pass 0: q (l2norm + qemb + scale), coalesced f32 store ----
    #pragma unroll
    for (int j=0;j<6;++j){
        const int ct = wv*6+j;
        if ((ct>>3)==0){
            const int head = ct&7;
            float tm = temp[head];
            float sps = (tm>15.f)?tm:log1pf(__expf(tm));
            float qe = qemb[head*HD + lr];
            #pragma unroll
            for (int rt=0;rt<4;++rt){
                #pragma unroll
                for (int r=0;r<4;++r){
                    float v = acc[rt][j][r];
                    float s = v*v;
                    s += __shfl_xor(s,1); s += __shfl_xor(s,2);
                    s += __shfl_xor(s,4); s += __shfl_xor(s,8);
                    v *= 1.0f/fmaxf(sqrtf(s),1e-12f);
                    v = (v+qe)*(slog[rt][r]*sps);
                    xs[(rt*16+lg*4+r)*132 + head*16 + lr] = v;
                }
            }
        }
    }
    __syncthreads();
    #pragma unroll
    for (int i=0;i<8;++i){
        int p = i*256 + t;
        int row = p>>5, c4 = p&31;
        float4 v = *reinterpret_cast<const float4*>(xs + row*132 + c4*4);
        *reinterpret_cast<float4*>(qbuf + (size_t)(m0+row)*CC + c4*4) = v;
    }
    __syncthreads();

    // ---- pass 1: k (l2norm), coalesced f32 store ----
    #pragma unroll
    for (int j=0;j<6;++j){
        const int ct = wv*6+j;
        if ((ct>>3)==1){
            const int kc = ct&7;
            #pragma unroll
            for (int rt=0;rt<4;++rt){
                #pragma unroll
                for (int r=0;r<4;++r){
                    float v = acc[rt][j][r];
                    float s = v*v;
                    s += __shfl_xor(s,1); s += __shfl_xor(s,2);
                    s += __shfl_xor(s,4); s += __shfl_xor(s,8);
                    v *= 1.0f/fmaxf(sqrtf(s),1e-12f);
                    xs[(rt*16+lg*4+r)*132 + kc*16 + lr] = v;
                }
            }
        }
    }
    __syncthreads();
    #pragma unroll
    for (int i=0;i<8;++i){
        int p = i*256 + t;
        int row = p>>5, c4 = p&31;
        float4 v = *reinterpret_cast<const float4*>(xs + row*132 + c4*4);
        *reinterpret_cast<float4*>(kbuf + (size_t)(m0+row)*CC + c4*4) = v;
    }
    __syncthreads();

    // ---- pass 2: v (raw), packed-bf16 coalesced store ----
    #pragma unroll
    for (int j=0;j<6;++j){
        const int ct = wv*6+j;
        if ((ct>>3)==2){
            const int vc = ct&7;
            #pragma unroll
            for (int rt=0;rt<4;++rt){
                #pragma unroll
                for (int r=0;r<4;++r)
                    xs[(rt*16+lg*4+r)*132 + vc*16 + lr] = acc[rt][j][r];
            }
        }
    }
    __syncthreads();
    #pragma unroll
    for (int i=0;i<4;++i){
        int p = i*256 + t;
        int row = p>>4, c8 = p&15;
        const float* src = xs + row*132 + c8*8;
        float4 a0 = *reinterpret_cast<const float4*>(src);
        float4 a1 = *reinterpret_cast<const float4*>(src+4);
        uint4 o;
        o.x = (unsigned)f2bf(a0.x) | ((unsigned)f2bf(a0.y)<<16);
        o.y = (unsigned)f2bf(a0.z) | ((unsigned)f2bf(a0.w)<<16);
        o.z = (unsigned)f2bf(a1.x) | ((unsigned)f2bf(a1.y)<<16);
        o.w = (unsigned)f2bf(a1.z) | ((unsigned)f2bf(a1.w)<<16);
        *reinterpret_cast<uint4*>(vbuf + (size_t)(m0+row)*CC + c8*8) = o;
    }
}

// ---------- Kernel B: 27-neighbor attention (byte-identical, measured-working) ----------
__global__ __launch_bounds__(256)
void attn_kernel(float* __restrict__ qa,
                 const float* __restrict__ kbuf,
                 const unsigned short* __restrict__ vbuf,
                 const float* __restrict__ rpb)
{
    const int t = threadIdx.x;
    const int tok = blockIdx.x*32 + (t>>3);
    const int h = t&7;
    const int n = tok % NTOK;
    const int z = n / HWW; const int rem = n - z*HWW;
    const int y = rem / WW; const int xx = rem - y*WW;
    const int tokbase = tok - n;

    float qf[16];
    {
        const float4* qp = reinterpret_cast<const float4*>(qa + (size_t)tok*CC + h*HD);
        float4 a=qp[0],b=qp[1],c=qp[2],d=qp[3];
        qf[0]=a.x;qf[1]=a.y;qf[2]=a.z;qf[3]=a.w;
        qf[4]=b.x;qf[5]=b.y;qf[6]=b.z;qf[7]=b.w;
        qf[8]=c.x;qf[9]=c.y;qf[10]=c.z;qf[11]=c.w;
        qf[12]=d.x;qf[13]=d.y;qf[14]=d.z;qf[15]=d.w;
    }

    float l[27];
    #pragma unroll
    for (int j=0;j<27;++j){
        const int dz=j/9, dy=(j/3)%3, dx=j%3;
        int z2=z+dz-1, y2=y+dy-1, x2=xx+dx-1;
        bool valid = ((unsigned)z2<DD) && ((unsigned)y2<HH) && ((unsigned)x2<WW);
        int row2 = valid ? (tokbase + z2*HWW + y2*WW + x2) : tok;
        const float4* kp = reinterpret_cast<const float4*>(kbuf + (size_t)row2*CC + h*HD);
        float4 ka=kp[0],kb=kp[1],kc=kp[2],kd=kp[3];
        float kk[16]={ka.x,ka.y,ka.z,ka.w, kb.x,kb.y,kb.z,kb.w,
                      kc.x,kc.y,kc.z,kc.w, kd.x,kd.y,kd.z,kd.w};
        float s = 0.f;
        #pragma unroll
        for (int d=0;d<16;++d) s = fmaf(qf[d],kk[d],s);
        l[j] = valid ? (s + rpb[h*27+j]) : -1e30f;
    }

    float m = l[0];
    #pragma unroll
    for (int j=1;j<27;++j) m = fmaxf(m,l[j]);
    float sum=0.f;
    #pragma unroll
    for (int j=0;j<27;++j){ float e=__expf(l[j]-m); l[j]=e; sum+=e; }
    float rs = 1.0f/sum;

    float o[16];
    #pragma unroll
    for (int d=0;d<16;++d) o[d]=0.f;
    #pragma unroll
    for (int j=0;j<27;++j){
        const int dz=j/9, dy=(j/3)%3, dx=j%3;
        int z2=z+dz-1, y2=y+dy-1, x2=xx+dx-1;
        bool valid = ((unsigned)z2<DD) && ((unsigned)y2<HH) && ((unsigned)x2<WW);
        int row2 = valid ? (tokbase + z2*HWW + y2*WW + x2) : tok;
        const uint4* vp = reinterpret_cast<const uint4*>(vbuf + (size_t)row2*CC + h*HD);
        uint4 va=vp[0], vb=vp[1];
        unsigned int vw[8]={va.x,va.y,va.z,va.w,vb.x,vb.y,vb.z,vb.w};
        float w = l[j];
        #pragma unroll
        for (int q2=0;q2<8;++q2){
            o[2*q2]   = fmaf(w, bf2f((unsigned short)(vw[q2]&0xffffu)), o[2*q2]);
            o[2*q2+1] = fmaf(w, bf2f((unsigned short)(vw[q2]>>16)),     o[2*q2+1]);
        }
    }
    #pragma unroll
    for (int d=0;d<16;++d) o[d]*=rs;
    float4* op = reinterpret_cast<float4*>(qa + (size_t)tok*CC + h*HD);
    op[0]=make_float4(o[0],o[1],o[2],o[3]);
    op[1]=make_float4(o[4],o[5],o[6],o[7]);
    op[2]=make_float4(o[8],o[9],o[10],o[11]);
    op[3]=make_float4(o[12],o[13],o[14],o[15]);
}

// ---------- Kernel C: proj — LDS-staged bf16 A, split-B, LDS-transpose epilogue ----------
__global__ __launch_bounds__(256,4)
void proj_kernel(const float* __restrict__ ao,
                 const unsigned short* __restrict__ pwfhi, const unsigned short* __restrict__ pwflo,
                 const float* __restrict__ pb, float* __restrict__ out)
{
    __shared__ float xs[64*132];
    const int t  = threadIdx.x;
    const int wv = t>>6;
    const int l  = t&63;
    const int lr = l&15;
    const int lg = l>>4;
    const int m0 = blockIdx.x*64;

    #pragma unroll
    for (int i=0;i<8;++i){
        int p = i*256 + t;
        int row = p>>5, c = p&31;
        float4 v = *reinterpret_cast<const float4*>(ao + (size_t)(m0+row)*CC + c*4);
        int ch = row*32 + (c ^ (row&7));
        *reinterpret_cast<float4*>(xs + ch*4) = v;
    }
    __syncthreads();

    f32x4 acc[4][2];
    #pragma unroll
    for (int j=0;j<2;++j){
        float b = pb[(wv*2+j)*16 + lr];
        #pragma unroll
        for (int rt=0;rt<4;++rt) acc[rt][j] = (f32x4){b,b,b,b};
    }

    #pragma unroll
    for (int ks=0; ks<4; ++ks){
        bf16x8 ahi[4];
        #pragma unroll
        for (int rt=0;rt<4;++rt){
            int row = rt*16 + lr;
            int c0  = ks*8 + lg*2;
            float4 a0 = *reinterpret_cast<const float4*>(xs + (row*32 + ( c0   ^(row&7)))*4);
            float4 a1 = *reinterpret_cast<const float4*>(xs + (row*32 + ((c0+1)^(row&7)))*4);
            float xf[8] = {a0.x,a0.y,a0.z,a0.w, a1.x,a1.y,a1.z,a1.w};
            #pragma unroll
            for (int jj=0;jj<8;++jj) ahi[rt][jj] = (short)f2bf(xf[jj]);
        }
        #pragma unroll
        for (int j=0;j<2;++j){
            const int ct = wv*2+j;
            const size_t off = (size_t)(((ct*4+ks)*64 + l))*8;
            bf16x8 bhi = *reinterpret_cast<const bf16x8*>(pwfhi + off);
            bf16x8 blo = *reinterpret_cast<const bf16x8*>(pwflo + off);
            #pragma unroll
            for (int rt=0;rt<4;++rt){
                acc[rt][j] = __builtin_amdgcn_mfma_f32_16x16x32_bf16(ahi[rt], bhi, acc[rt][j], 0,0,0);
                acc[rt][j] = __builtin_amdgcn_mfma_f32_16x16x32_bf16(ahi[rt], blo, acc[rt][j], 0,0,0);
            }
        }
    }

    __syncthreads();
    #pragma unroll
    for (int j=0;j<2;++j){
        const int col = (wv*2+j)*16 + lr;
        #pragma unroll
        for (int rt=0;rt<4;++rt){
            #pragma unroll
            for (int r=0;r<4;++r)
                xs[(rt*16+lg*4+r)*132 + col] = acc[rt][j][r];
        }
    }
    __syncthreads();
    #pragma unroll
    for (int i=0;i<8;++i){
        int p = i*256 + t;
        int row = p>>5, c4 = p&31;
        float4 v = *reinterpret_cast<const float4*>(xs + row*132 + c4*4);
        *reinterpret_cast<float4*>(out + (size_t)(m0+row)*CC + c4*4) = v;
    }
}

extern "C" void kernel_launch(void* const* d_in, const int* in_sizes, int n_in,
                              void* d_out, int out_size, void* d_ws, size_t ws_size,
                              hipStream_t stream)
{
    const float* x    = (const float*)d_in[0];
    const float* qw   = (const float*)d_in[1];
    const float* qb   = (const float*)d_in[2];
    const float* kvw  = (const float*)d_in[3];
    const float* kvb  = (const float*)d_in[4];
    const float* pw   = (const float*)d_in[5];
    const float* pb   = (const float*)d_in[6];
    const float* temp = (const float*)d_in[7];
    const float* qemb = (const float*)d_in[8];
    const float* rpb  = (const float*)d_in[9];

    float* qbuf = (float*)d_ws;                                        // 51.4 MB
    float* kbuf = qbuf + (size_t)MTOT*CC;                              // 51.4 MB
    unsigned short* vbuf = (unsigned short*)(kbuf + (size_t)MTOT*CC);  // 25.7 MB
    unsigned short* wfhi  = vbuf + (size_t)MTOT*CC;                    // 96 KB
    unsigned short* wflo  = wfhi + 384*CC;
    unsigned short* pwfhi = wflo + 384*CC;
    unsigned short* pwflo = pwfhi + CC*CC;

    hipLaunchKernelGGL(wsplit_kernel, dim3(256), dim3(256), 0, stream,
                       qw,kvw,pw,wfhi,wflo,pwfhi,pwflo);
    hipLaunchKernelGGL(qkv_kernel, dim3(MTOT/64), dim3(256), 0, stream,
                       x,qb,kvb,wfhi,wflo,temp,qemb,qbuf,kbuf,vbuf);
    hipLaunchKernelGGL(attn_kernel, dim3(MTOT/32), dim3(256), 0, stream,
                       qbuf,kbuf,vbuf,rpb);
    hipLaunchKernelGGL(proj_kernel, dim3(MTOT/64), dim3(256), 0, stream,
                       qbuf,pwfhi,pwflo,pb,(float*)d_out);
}

// Round 14
// 418.270 us; speedup vs baseline: 1.1954x; 1.1954x over previous
//
#include <hip/hip_runtime.h>

#define DD 8
#define HH 56
#define WW 56
#define HWW (HH*WW)
#define NTOK (DD*HH*WW)      // 25088
#define BB 4
#define CC 128
#define NH 8
#define HD 16
#define MTOT (BB*NTOK)       // 100352

typedef __attribute__((ext_vector_type(8))) short bf16x8;
typedef __attribute__((ext_vector_type(4))) float f32x4;

__device__ __forceinline__ unsigned short f2bf(float f){
    unsigned int u = __float_as_uint(f);
    u += 0x7FFFu + ((u>>16)&1u);
    return (unsigned short)(u>>16);
}
__device__ __forceinline__ float bf2f(unsigned short s){
    return __uint_as_float(((unsigned int)s)<<16);
}

// ---------- Pre-kernel: weights -> FRAGMENT-ORDERED bf16 hi/lo (unchanged) ----------
__global__ __launch_bounds__(256)
void wsplit_kernel(const float* __restrict__ qw, const float* __restrict__ kvw,
                   const float* __restrict__ pw,
                   unsigned short* __restrict__ wfhi, unsigned short* __restrict__ wflo,
                   unsigned short* __restrict__ pwfhi, unsigned short* __restrict__ pwflo)
{
    int idx = blockIdx.x*256 + threadIdx.x;   // 0..65535
    int e  = idx&7;
    int l  = (idx>>3)&63;
    int ks = (idx>>9)&3;
    int ct = idx>>11;                         // 0..31
    int lr = l&15, lg = l>>4;
    int k  = ks*32 + lg*8 + e;
    if (ct < 24){
        int c = ct*16 + lr;
        float s = (c<CC) ? qw[c*CC+k] : kvw[(c-CC)*CC+k];
        unsigned short h = f2bf(s);
        unsigned short lo = f2bf(s - bf2f(h));
        wfhi[idx]=h; wflo[idx]=lo;
    } else {
        int c = (ct-24)*16 + lr;
        float s = pw[c*CC+k];
        unsigned short h = f2bf(s);
        unsigned short lo = f2bf(s - bf2f(h));
        int o = idx - 49152;
        pwfhi[o]=h; pwflo[o]=lo;
    }
}

// ---------- Kernel A: QKV — LDS-staged A, fragment B, no spill (256,2) ----------
__global__ __launch_bounds__(256,2)
void qkv_kernel(const float* __restrict__ x,
                const float* __restrict__ qb, const float* __restrict__ kvb,
                const unsigned short* __restrict__ wfhi, const unsigned short* __restrict__ wflo,
                const float* __restrict__ temp, const float* __restrict__ qemb,
                float* __restrict__ qbuf, float* __restrict__ kbuf,
                unsigned short* __restrict__ vbuf)
{
    __shared__ float xs[64*128];              // 32KB, chunk-swizzled
    const int t  = threadIdx.x;
    const int wv = t>>6;
    const int l  = t&63;
    const int lr = l&15;
    const int lg = l>>4;
    const int m0 = blockIdx.x*64;

    // stage A: coalesced global read, XOR chunk-swizzled LDS write (16B chunk)
    #pragma unroll
    for (int i=0;i<8;++i){
        int p = i*256 + t;
        int row = p>>5, c = p&31;
        float4 v = *reinterpret_cast<const float4*>(x + (size_t)(m0+row)*CC + c*4);
        int ch = row*32 + (c ^ (row&7));
        *reinterpret_cast<float4*>(xs + ch*4) = v;
    }
    __syncthreads();

    f32x4 acc[4][6];
    #pragma unroll
    for (int j=0;j<6;++j){
        int col = (wv*6+j)*16 + lr;
        float b = (col<CC) ? qb[col] : kvb[col-CC];
        #pragma unroll
        for (int rt=0;rt<4;++rt) acc[rt][j] = (f32x4){b,b,b,b};
    }

    #pragma unroll
    for (int ks=0; ks<4; ++ks){
        bf16x8 ahi[4], alo[4];
        #pragma unroll
        for (int rt=0;rt<4;++rt){
            int row = rt*16 + lr;
            int c0  = ks*8 + lg*2;
            float4 a0 = *reinterpret_cast<const float4*>(xs + (row*32 + ( c0   ^(row&7)))*4);
            float4 a1 = *reinterpret_cast<const float4*>(xs + (row*32 + ((c0+1)^(row&7)))*4);
            float xf[8] = {a0.x,a0.y,a0.z,a0.w, a1.x,a1.y,a1.z,a1.w};
            #pragma unroll
            for (int jj=0;jj<8;++jj){
                unsigned short h = f2bf(xf[jj]);
                unsigned short lo2 = f2bf(xf[jj] - bf2f(h));
                ahi[rt][jj] = (short)h;
                alo[rt][jj] = (short)lo2;
            }
        }
        #pragma unroll
        for (int j=0;j<6;++j){
            const int ct = wv*6+j;
            const size_t off = (size_t)(((ct*4+ks)*64 + l))*8;
            bf16x8 bhi = *reinterpret_cast<const bf16x8*>(wfhi + off);
            bf16x8 blo = *reinterpret_cast<const bf16x8*>(wflo + off);
            #pragma unroll
            for (int rt=0;rt<4;++rt){
                acc[rt][j] = __builtin_amdgcn_mfma_f32_16x16x32_bf16(ahi[rt], bhi, acc[rt][j], 0,0,0);
                acc[rt][j] = __builtin_amdgcn_mfma_f32_16x16x32_bf16(alo[rt], bhi, acc[rt][j], 0,0,0);
                acc[rt][j] = __builtin_amdgcn_mfma_f32_16x16x32_bf16(ahi[rt], blo, acc[rt][j], 0,0,0);
            }
        }
    }

    // ---- postprocess + scalar store (proven exact-ideal WRITE in r3/r9) ----
    float slog[4][4];
    #pragma unroll
    for (int rt=0;rt<4;++rt){
        #pragma unroll
        for (int r=0;r<4;++r){
            int row = m0 + rt*16 + lg*4 + r;
            int n = row % NTOK;
            int z = n / HWW; int rem = n - z*HWW;
            int y = rem / WW; int xx = rem - y*WW;
            const float L2c = 0.69314718f, L3c = 1.09861229f;
            slog[rt][r] = ((z==0||z==DD-1)?L2c:L3c) + ((y==0||y==HH-1)?L2c:L3c) + ((xx==0||xx==WW-1)?L2c:L3c);
        }
    }

    #pragma unroll
    for (int j=0;j<6;++j){
        const int ct  = wv*6+j;
        const int sel = ct>>3;                 // 0=q,1=k,2=v
        const int head = ct & 7;
        float vals[4][4];
        #pragma unroll
        for (int rt=0;rt<4;++rt){
            #pragma unroll
            for (int r=0;r<4;++r) vals[rt][r] = acc[rt][j][r];
        }
        if (sel < 2){
            #pragma unroll
            for (int rt=0;rt<4;++rt){
                #pragma unroll
                for (int r=0;r<4;++r){
                    float s = vals[rt][r]*vals[rt][r];
                    s += __shfl_xor(s,1); s += __shfl_xor(s,2);
                    s += __shfl_xor(s,4); s += __shfl_xor(s,8);
                    float inv = 1.0f/fmaxf(sqrtf(s),1e-12f);
                    vals[rt][r] *= inv;
                }
            }
        }
        if (sel == 0){
            float tm = temp[head];
            float sps = (tm>15.f)?tm:log1pf(__expf(tm));
            float qe = qemb[head*HD + lr];
            #pragma unroll
            for (int rt=0;rt<4;++rt){
                #pragma unroll
                for (int r=0;r<4;++r)
                    vals[rt][r] = (vals[rt][r]+qe)*(slog[rt][r]*sps);
            }
        }
        #pragma unroll
        for (int rt=0;rt<4;++rt){
            #pragma unroll
            for (int r=0;r<4;++r){
                int row = m0 + rt*16 + lg*4 + r;
                if (sel==0){
                    qbuf[(size_t)row*CC + ct*16 + lr] = vals[rt][r];
                } else if (sel==1){
                    kbuf[(size_t)row*CC + (ct-8)*16 + lr] = vals[rt][r];
                } else {
                    vbuf[(size_t)row*CC + (ct-16)*16 + lr] = f2bf(vals[rt][r]);
                }
            }
        }
    }
}

// ---------- Kernel B: 27-neighbor attention (byte-identical, measured-working) ----------
__global__ __launch_bounds__(256)
void attn_kernel(float* __restrict__ qa,
                 const float* __restrict__ kbuf,
                 const unsigned short* __restrict__ vbuf,
                 const float* __restrict__ rpb)
{
    const int t = threadIdx.x;
    const int tok = blockIdx.x*32 + (t>>3);
    const int h = t&7;
    const int n = tok % NTOK;
    const int z = n / HWW; const int rem = n - z*HWW;
    const int y = rem / WW; const int xx = rem - y*WW;
    const int tokbase = tok - n;

    float qf[16];
    {
        const float4* qp = reinterpret_cast<const float4*>(qa + (size_t)tok*CC + h*HD);
        float4 a=qp[0],b=qp[1],c=qp[2],d=qp[3];
        qf[0]=a.x;qf[1]=a.y;qf[2]=a.z;qf[3]=a.w;
        qf[4]=b.x;qf[5]=b.y;qf[6]=b.z;qf[7]=b.w;
        qf[8]=c.x;qf[9]=c.y;qf[10]=c.z;qf[11]=c.w;
        qf[12]=d.x;qf[13]=d.y;qf[14]=d.z;qf[15]=d.w;
    }

    float l[27];
    #pragma unroll
    for (int j=0;j<27;++j){
        const int dz=j/9, dy=(j/3)%3, dx=j%3;
        int z2=z+dz-1, y2=y+dy-1, x2=xx+dx-1;
        bool valid = ((unsigned)z2<DD) && ((unsigned)y2<HH) && ((unsigned)x2<WW);
        int row2 = valid ? (tokbase + z2*HWW + y2*WW + x2) : tok;
        const float4* kp = reinterpret_cast<const float4*>(kbuf + (size_t)row2*CC + h*HD);
        float4 ka=kp[0],kb=kp[1],kc=kp[2],kd=kp[3];
        float kk[16]={ka.x,ka.y,ka.z,ka.w, kb.x,kb.y,kb.z,kb.w,
                      kc.x,kc.y,kc.z,kc.w, kd.x,kd.y,kd.z,kd.w};
        float s = 0.f;
        #pragma unroll
        for (int d=0;d<16;++d) s = fmaf(qf[d],kk[d],s);
        l[j] = valid ? (s + rpb[h*27+j]) : -1e30f;
    }

    float m = l[0];
    #pragma unroll
    for (int j=1;j<27;++j) m = fmaxf(m,l[j]);
    float sum=0.f;
    #pragma unroll
    for (int j=0;j<27;++j){ float e=__expf(l[j]-m); l[j]=e; sum+=e; }
    float rs = 1.0f/sum;

    float o[16];
    #pragma unroll
    for (int d=0;d<16;++d) o[d]=0.f;
    #pragma unroll
    for (int j=0;j<27;++j){
        const int dz=j/9, dy=(j/3)%3, dx=j%3;
        int z2=z+dz-1, y2=y+dy-1, x2=xx+dx-1;
        bool valid = ((unsigned)z2<DD) && ((unsigned)y2<HH) && ((unsigned)x2<WW);
        int row2 = valid ? (tokbase + z2*HWW + y2*WW + x2) : tok;
        const uint4* vp = reinterpret_cast<const uint4*>(vbuf + (size_t)row2*CC + h*HD);
        uint4 va=vp[0], vb=vp[1];
        unsigned int vw[8]={va.x,va.y,va.z,va.w,vb.x,vb.y,vb.z,vb.w};
        float w = l[j];
        #pragma unroll
        for (int q2=0;q2<8;++q2){
            o[2*q2]   = fmaf(w, bf2f((unsigned short)(vw[q2]&0xffffu)), o[2*q2]);
            o[2*q2+1] = fmaf(w, bf2f((unsigned short)(vw[q2]>>16)),     o[2*q2+1]);
        }
    }
    #pragma unroll
    for (int d=0;d<16;++d) o[d]*=rs;
    float4* op = reinterpret_cast<float4*>(qa + (size_t)tok*CC + h*HD);
    op[0]=make_float4(o[0],o[1],o[2],o[3]);
    op[1]=make_float4(o[4],o[5],o[6],o[7]);
    op[2]=make_float4(o[8],o[9],o[10],o[11]);
    op[3]=make_float4(o[12],o[13],o[14],o[15]);
}

// ---------- Kernel C: proj — LDS-staged bf16 A, split-B, no spill (256,2) ----------
__global__ __launch_bounds__(256,2)
void proj_kernel(const float* __restrict__ ao,
                 const unsigned short* __restrict__ pwfhi, const unsigned short* __restrict__ pwflo,
                 const float* __restrict__ pb, float* __restrict__ out)
{
    __shared__ float xs[64*128];
    const int t  = threadIdx.x;
    const int wv = t>>6;
    const int l  = t&63;
    const int lr = l&15;
    const int lg = l>>4;
    const int m0 = blockIdx.x*64;

    #pragma unroll
    for (int i=0;i<8;++i){
        int p = i*256 + t;
        int row = p>>5, c = p&31;
        float4 v = *reinterpret_cast<const float4*>(ao + (size_t)(m0+row)*CC + c*4);
        int ch = row*32 + (c ^ (row&7));
        *reinterpret_cast<float4*>(xs + ch*4) = v;
    }
    __syncthreads();

    f32x4 acc[4][2];
    #pragma unroll
    for (int j=0;j<2;++j){
        float b = pb[(wv*2+j)*16 + lr];
        #pragma unroll
        for (int rt=0;rt<4;++rt) acc[rt][j] = (f32x4){b,b,b,b};
    }

    #pragma unroll
    for (int ks=0; ks<4; ++ks){
        bf16x8 ahi[4];
        #pragma unroll
        for (int rt=0;rt<4;++rt){
            int row = rt*16 + lr;
            int c0  = ks*8 + lg*2;
            float4 a0 = *reinterpret_cast<const float4*>(xs + (row*32 + ( c0   ^(row&7)))*4);
            float4 a1 = *reinterpret_cast<const float4*>(xs + (row*32 + ((c0+1)^(row&7)))*4);
            float xf[8] = {a0.x,a0.y,a0.z,a0.w, a1.x,a1.y,a1.z,a1.w};
            #pragma unroll
            for (int jj=0;jj<8;++jj) ahi[rt][jj] = (short)f2bf(xf[jj]);
        }
        #pragma unroll
        for (int j=0;j<2;++j){
            const int ct = wv*2+j;
            const size_t off = (size_t)(((ct*4+ks)*64 + l))*8;
            bf16x8 bhi = *reinterpret_cast<const bf16x8*>(pwfhi + off);
            bf16x8 blo = *reinterpret_cast<const bf16x8*>(pwflo + off);
            #pragma unroll
            for (int rt=0;rt<4;++rt){
                acc[rt][j] = __builtin_amdgcn_mfma_f32_16x16x32_bf16(ahi[rt], bhi, acc[rt][j], 0,0,0);
                acc[rt][j] = __builtin_amdgcn_mfma_f32_16x16x32_bf16(ahi[rt], blo, acc[rt][j], 0,0,0);
            }
        }
    }

    #pragma unroll
    for (int j=0;j<2;++j){
        const int col = (wv*2+j)*16 + lr;
        #pragma unroll
        for (int rt=0;rt<4;++rt){
            #pragma unroll
            for (int r=0;r<4;++r){
                int row = m0 + rt*16 + lg*4 + r;
                out[(size_t)row*CC + col] = acc[rt][j][r];
            }
        }
    }
}

extern "C" void kernel_launch(void* const* d_in, const int* in_sizes, int n_in,
                              void* d_out, int out_size, void* d_ws, size_t ws_size,
                              hipStream_t stream)
{
    const float* x    = (const float*)d_in[0];
    const float* qw   = (const float*)d_in[1];
    const float* qb   = (const float*)d_in[2];
    const float* kvw  = (const float*)d_in[3];
    const float* kvb  = (const float*)d_in[4];
    const float* pw   = (const float*)d_in[5];
    const float* pb   = (const float*)d_in[6];
    const float* temp = (const float*)d_in[7];
    const float* qemb = (const float*)d_in[8];
    const float* rpb  = (const float*)d_in[9];

    float* qbuf = (float*)d_ws;                                        // 51.4 MB
    float* kbuf = qbuf + (size_t)MTOT*CC;                              // 51.4 MB
    unsigned short* vbuf = (unsigned short*)(kbuf + (size_t)MTOT*CC);  // 25.7 MB
    unsigned short* wfhi  = vbuf + (size_t)MTOT*CC;                    // 96 KB
    unsigned short* wflo  = wfhi + 384*CC;
    unsigned short* pwfhi = wflo + 384*CC;
    unsigned short* pwflo = pwfhi + CC*CC;

    hipLaunchKernelGGL(wsplit_kernel, dim3(256), dim3(256), 0, stream,
                       qw,kvw,pw,wfhi,wflo,pwfhi,pwflo);
    hipLaunchKernelGGL(qkv_kernel, dim3(MTOT/64), dim3(256), 0, stream,
                       x,qb,kvb,wfhi,wflo,temp,qemb,qbuf,kbuf,vbuf);
    hipLaunchKernelGGL(attn_kernel, dim3(MTOT/32), dim3(256), 0, stream,
                       qbuf,kbuf,vbuf,rpb);
    hipLaunchKernelGGL(proj_kernel, dim3(MTOT/64), dim3(256), 0, stream,
                       qbuf,pwfhi,pwflo,pb,(float*)d_out);
}